// Round 14
// baseline (398.246 us; speedup 1.0000x reference)
//
#include <hip/hip_runtime.h>
#include <hip/hip_bf16.h>

using bf16 = __hip_bfloat16;

typedef __attribute__((ext_vector_type(8))) short short8;
typedef __attribute__((ext_vector_type(4))) float f32x4;

constexpr int Bb = 32, Dd = 256, HWw = 4096, Kk = 256, Ff = 2048;
constexpr float TEMP_INV = 1.0f / 0.07f;
constexpr float EPSf = 1e-6f;
constexpr float NORM_EPSf = 1e-12f;
constexpr float LN_EPSf = 1e-5f;
constexpr size_t PKD = (size_t)Bb * Kk * Dd;   // one t2 partial (2M floats = 8 MB)

static __device__ __forceinline__ float b2f(bf16 v) { return __bfloat162float(v); }
static __device__ __forceinline__ bf16 f2b(float v) { return __float2bfloat16(v); }

// Fragment-order conventions (16x16x32 MFMA, K-step 32):
//   element (row, k): set = k>>5, q2 = (k>>3)&3, j = k&7
//   256-row group (tnbf, attn_bf, xb_bf): fi = (row>>4)*64 + q2*16 + (row&15); 1024 frags/step
//   64-row group (tbf/w1bf/w2bf):         fi = ((row&63)>>4)*64 + q2*16 + (row&15); 256 frags/step
//   32-row group (k_ffn rp tile):         fi = ((row&31)>>4)*64 + q2*16 + (row&15); 128 frags/set
// Reader identity: addr = set_base + (mtile_local*64 + lane)*8  (lane = q2*16 + row&15)
// LDS repack swizzle (bank-spread, involution): fi_sw = fi ^ ((fi>>3)&3)
//
// Config provenance (measured):
//   k_dots: R5/R10 pair-wise hw-64 + bounds(256,3), VGPR 80 -> 91-108 us session-dependent.
//     R11 hw-32 REGRESSED (occupancy not binding). R6 superstep SPILLED.
//   k_gemm2: R8 hs-4 K-split partials, grid 2048.
//   k_ffn: fused ffn1+ffn2+LN_out (R13-proven, 388.9 us best).
//   THIS ROUND: w1bf/w2bf get dedicated ws (+2MB, 174<=180 proven) -> k_prew loses its
//     after-gemm2 ordering constraint and merges into k_tn (k_tnw). 6 dispatches -> 5.
//   Evidence R7-R13: mid-pipe is launch/drain-bound; each dispatch removal ~4-15 us.

// ---------------- k_tnw: tn (l2norm tgt -> tnbf, zero S) + prew (w1/w2 -> frag order) ----------------
__global__ __launch_bounds__(64) void k_tnw(const float* __restrict__ tgt,
                                            bf16* __restrict__ tnbf,
                                            float* __restrict__ S,
                                            const float* __restrict__ w1,
                                            const float* __restrict__ w2,
                                            bf16* __restrict__ w1bf,
                                            bf16* __restrict__ w2bf) {
  int bidx = blockIdx.x;
  int lane = threadIdx.x;
  if (bidx < Bb * Kk) {
    int row = bidx;                // b*256 + slot
    int b = row >> 8, slot = row & 255;
    if (lane == 0) S[row] = 0.f;   // replaces hipMemsetAsync(S) (k_dots runs after)
    const float* src = tgt + (size_t)row * Dd + lane * 4;
    float v[4];
#pragma unroll
    for (int u = 0; u < 4; u++) v[u] = src[u];
    float ss = v[0] * v[0] + v[1] * v[1] + v[2] * v[2] + v[3] * v[3];
#pragma unroll
    for (int m = 32; m >= 1; m >>= 1) ss += __shfl_xor(ss, m, 64);
    float inv = 1.0f / fmaxf(sqrtf(ss), NORM_EPSf);
    bf16 o[4] __attribute__((aligned(8)));
#pragma unroll
    for (int u = 0; u < 4; u++) o[u] = f2b(v[u] * inv);
    int s = lane >> 3;
    int q2 = (lane >> 1) & 3;
    int jh = (lane & 1) * 4;
    size_t fi = (size_t)((slot >> 4) * 64 + q2 * 16 + (slot & 15));
    *(float2*)(tnbf + ((size_t)(b * 8 + s) * 1024 + fi) * 8 + jh) = *(float2*)o;
  } else if (bidx < Bb * Kk + Ff) {
    int f = bidx - Bb * Kk;        // 0..2047
    const float* src = w1 + (size_t)f * Dd + lane * 4;
    bf16 o[4] __attribute__((aligned(8)));
#pragma unroll
    for (int u = 0; u < 4; u++) o[u] = f2b(src[u]);
    int s = lane >> 3;
    int q2 = (lane >> 1) & 3;
    int jh = (lane & 1) * 4;
    size_t fi = (size_t)(((f & 63) >> 4) * 64 + q2 * 16 + (f & 15));
    *(float2*)(w1bf + ((size_t)((f >> 6) * 8 + s) * 256 + fi) * 8 + jh) = *(float2*)o;
  } else {
    int d = bidx - Bb * Kk - Ff;   // 0..255
    const float* src = w2 + (size_t)d * Ff + lane * 32;
    size_t gbase = (size_t)((d >> 6) * 64 + lane) * 256;
    int fbase = ((d & 63) >> 4) * 64 + (d & 15);
#pragma unroll
    for (int q2 = 0; q2 < 4; q2++) {
      float4 v0 = *(const float4*)(src + q2 * 8);
      float4 v1 = *(const float4*)(src + q2 * 8 + 4);
      bf16 o[8] __attribute__((aligned(16)));
      o[0] = f2b(v0.x); o[1] = f2b(v0.y); o[2] = f2b(v0.z); o[3] = f2b(v0.w);
      o[4] = f2b(v1.x); o[5] = f2b(v1.y); o[6] = f2b(v1.z); o[7] = f2b(v1.w);
      *(float4*)(w2bf + (gbase + fbase + q2 * 16) * 8) = *(float4*)o;
    }
  }
}

#define MFMA16(a, b, c) __builtin_amdgcn_mfma_f32_16x16x32_bf16(a, b, c, 0, 0, 0)

// ---------------- k_dots: softmax(slots) -> attn_bf (frag order), xb_bf (frag order), S ----------------
// R5 config: pair-wise double-buffered pipeline at 3 waves/SIMD, bounds(256,3), VGPR 80.
__global__ __launch_bounds__(256, 3) void k_dots(const bf16* __restrict__ tnbf,
                                                 const float* __restrict__ x,
                                                 bf16* __restrict__ xb_bf,
                                                 bf16* __restrict__ attn_bf,
                                                 float* __restrict__ S) {
  __shared__ __align__(16) char smem[23296];
  bf16* Bs = (bf16*)smem;                    // [4][2080]
  float* ssred = (float*)(smem + 16640);     // [64*17]
  float* nxl = (float*)(smem + 20992);       // [64]
  float* red = (float*)(smem + 21248);       // [512]
  int b = blockIdx.x >> 6;
  int hw0 = (blockIdx.x & 63) * 64;
  int tid = threadIdx.x;
  int wave = tid >> 6, lane = tid & 63;
  int quad = lane >> 4, nl = lane & 15;

  int dp = tid >> 4;           // 0..15
  int ch = tid & 15;           // 0..15
  int qb = dp >> 2;
  int jb = (dp & 3) * 2;

  f32x4 acc[4][4];
#pragma unroll
  for (int i = 0; i < 4; i++)
#pragma unroll
    for (int j = 0; j < 4; j++) acc[i][j] = (f32x4){0.f, 0.f, 0.f, 0.f};
  float ssp[4] = {0.f, 0.f, 0.f, 0.f};

  int spx = (hw0 >> 5) + (ch >> 3);
  int q2x = (ch >> 1) & 3;
  int jx = (ch & 1) * 4;

  const float* xbase = x + (size_t)((b << 8) + 2 * dp) * HWw + hw0 + ch * 4;
  float4 va4[2], vb4[2];
#pragma unroll
  for (int q = 0; q < 2; q++) {
    const float* xr = xbase + (size_t)(q * 32) * HWw;
    va4[q] = *(const float4*)xr;
    vb4[q] = *(const float4*)(xr + HWw);
  }
  short8 afp[4];
  {
    const bf16* ts0 = tnbf + (size_t)(b * 8) * 1024 * 8;
#pragma unroll
    for (int mt = 0; mt < 4; mt++)
      afp[mt] = *(const short8*)(ts0 + (size_t)(((wave << 2) + mt) * 64 + lane) * 8);
  }

#pragma unroll 1
  for (int p = 0; p < 4; p++) {
    bf16* bsb = Bs + (p & 1) * 2 * 2080;
    bf16 paS[2][4] __attribute__((aligned(8)));
    bf16 pbS[2][4] __attribute__((aligned(8)));
#pragma unroll
    for (int q = 0; q < 2; q++) {
      float vva[4] = {va4[q].x, va4[q].y, va4[q].z, va4[q].w};
      float vvb[4] = {vb4[q].x, vb4[q].y, vb4[q].z, vb4[q].w};
#pragma unroll
      for (int jj = 0; jj < 4; jj++) {
        ssp[jj] += vva[jj] * vva[jj] + vvb[jj] * vvb[jj];
        paS[q][jj] = f2b(vva[jj]);
        pbS[q][jj] = f2b(vvb[jj]);
      }
#pragma unroll
      for (int jj = 0; jj < 4; jj++) {
        int hwl = ch * 4 + jj;
        int nt = hwl >> 4;
        int li = (qb << 4) | (hwl & 15);
        union { bf16 h[2]; unsigned int u; } pk;
        pk.h[0] = paS[q][jj];
        pk.h[1] = pbS[q][jj];
        *(unsigned int*)&bsb[q * 2080 + nt * 520 + li * 8 + jb] = pk.u;
      }
    }
    __syncthreads();

#pragma unroll
    for (int q = 0; q < 2; q++) {
      int s = 2 * p + q;
      int d0r = s * 32 + 2 * dp;
      int fiA = (d0r >> 4) * 64 + q2x * 16 + (d0r & 15);
      size_t base = ((size_t)(b * 128) + spx) * 1024;
      *(float2*)(xb_bf + (base + fiA) * 8 + jx) = *(float2*)paS[q];
      *(float2*)(xb_bf + (base + fiA + 1) * 8 + jx) = *(float2*)pbS[q];
    }
    if (p < 3) {
#pragma unroll
      for (int q = 0; q < 2; q++) {
        const float* xr = xbase + (size_t)(((p + 1) * 2 + q) * 32) * HWw;
        va4[q] = *(const float4*)xr;
        vb4[q] = *(const float4*)(xr + HWw);
      }
    }
#pragma unroll
    for (int q = 0; q < 2; q++) {
      int s = 2 * p + q;
      short8 af[4];
#pragma unroll
      for (int mt = 0; mt < 4; mt++) af[mt] = afp[mt];
      if (s < 7) {
        const bf16* tsrc = tnbf + (size_t)(b * 8 + s + 1) * 1024 * 8;
#pragma unroll
        for (int mt = 0; mt < 4; mt++)
          afp[mt] = *(const short8*)(tsrc + (size_t)(((wave << 2) + mt) * 64 + lane) * 8);
      }
      short8 bfv[4];
#pragma unroll
      for (int nt = 0; nt < 4; nt++)
        bfv[nt] = *(const short8*)(bsb + q * 2080 + nt * 520 + lane * 8);
#pragma unroll
      for (int mt = 0; mt < 4; mt++)
#pragma unroll
        for (int nt = 0; nt < 4; nt++) acc[mt][nt] = MFMA16(af[mt], bfv[nt], acc[mt][nt]);
    }
  }

#pragma unroll
  for (int jj = 0; jj < 4; jj++) ssred[(ch * 4 + jj) * 17 + dp] = ssp[jj];
  __syncthreads();
  if (tid < 64) {
    float sum = 0.f;
#pragma unroll
    for (int i = 0; i < 16; i++) sum += ssred[tid * 17 + i];
    nxl[tid] = TEMP_INV / fmaxf(sqrtf(sum), NORM_EPSf);
  }
  __syncthreads();

  float sc[4];
#pragma unroll
  for (int nt = 0; nt < 4; nt++) sc[nt] = nxl[nt * 16 + nl];
#pragma unroll
  for (int mt = 0; mt < 4; mt++)
#pragma unroll
    for (int nt = 0; nt < 4; nt++)
#pragma unroll
      for (int r = 0; r < 4; r++) acc[mt][nt][r] *= sc[nt];

  float* red2 = red + 256;

  float pmax[4];
#pragma unroll
  for (int nt = 0; nt < 4; nt++) {
    float m = acc[0][nt][0];
#pragma unroll
    for (int mt = 0; mt < 4; mt++)
#pragma unroll
      for (int r = 0; r < 4; r++) m = fmaxf(m, acc[mt][nt][r]);
    m = fmaxf(m, __shfl_xor(m, 16, 64));
    m = fmaxf(m, __shfl_xor(m, 32, 64));
    pmax[nt] = m;
  }
  if (lane < 16) {
#pragma unroll
    for (int nt = 0; nt < 4; nt++) red[((wave << 2) + nt) * 16 + nl] = pmax[nt];
  }
  __syncthreads();
  float cmax[4];
#pragma unroll
  for (int nt = 0; nt < 4; nt++) {
    float m = red[nt * 16 + nl];
#pragma unroll
    for (int w2 = 1; w2 < 4; w2++) m = fmaxf(m, red[((w2 << 2) + nt) * 16 + nl]);
    cmax[nt] = m;
  }

  float psum[4];
#pragma unroll
  for (int nt = 0; nt < 4; nt++) {
    float s = 0.f;
#pragma unroll
    for (int mt = 0; mt < 4; mt++)
#pragma unroll
      for (int r = 0; r < 4; r++) {
        float e = __expf(acc[mt][nt][r] - cmax[nt]);
        acc[mt][nt][r] = e;
        s += e;
      }
    s += __shfl_xor(s, 16, 64);
    s += __shfl_xor(s, 32, 64);
    psum[nt] = s;
  }
  if (lane < 16) {
#pragma unroll
    for (int nt = 0; nt < 4; nt++) red2[((wave << 2) + nt) * 16 + nl] = psum[nt];
  }
  __syncthreads();
  float ci[4];
#pragma unroll
  for (int nt = 0; nt < 4; nt++) {
    float s = 0.f;
#pragma unroll
    for (int w2 = 0; w2 < 4; w2++) s += red2[((w2 << 2) + nt) * 16 + nl];
    ci[nt] = 1.0f / s;
  }

#pragma unroll
  for (int mt = 0; mt < 4; mt++) {
    int slotg = (b << 8) + (wave << 6) + (mt << 4) + (quad << 2);
#pragma unroll
    for (int r = 0; r < 4; r++) {
      float rs = 0.f;
#pragma unroll
      for (int nt = 0; nt < 4; nt++) {
        bf16 hb = f2b(acc[mt][nt][r] * ci[nt] + EPSf);
        float q = b2f(hb);
        acc[mt][nt][r] = q;
        rs += q;
      }
      rs += __shfl_xor(rs, 1, 64);
      rs += __shfl_xor(rs, 2, 64);
      rs += __shfl_xor(rs, 4, 64);
      rs += __shfl_xor(rs, 8, 64);
      if (nl == 0) atomicAdd(&S[slotg + r], rs);
    }
  }

  __syncthreads();
  bf16* rp = (bf16*)smem;
  int jat = nl & 7;
#pragma unroll
  for (int h = 0; h < 2; h++) {
#pragma unroll
    for (int mt = 0; mt < 4; mt++) {
      int fi0 = ((wave << 2) + mt) * 64 + (quad << 2);
#pragma unroll
      for (int ntl = 0; ntl < 2; ntl++) {
        int nt = (h << 1) + ntl;
        int q2p = (ntl << 1) + (nl >> 3);
#pragma unroll
        for (int r = 0; r < 4; r++) {
          int fi = fi0 + q2p * 16 + r;
          int fisw = fi ^ ((fi >> 3) & 3);
          rp[fisw * 8 + jat] = f2b(acc[mt][nt][r]);
        }
      }
    }
    __syncthreads();
    size_t gbase = ((size_t)(b * 128) + (hw0 >> 5) + h) * 1024 * 8;
#pragma unroll
    for (int u = 0; u < 4; u++) {
      int fl = u * 256 + tid;
      int fg = fl ^ ((fl >> 3) & 3);
      short8 vv = *(const short8*)(rp + (size_t)fl * 8);
      *(short8*)(attn_bf + gbase + (size_t)fg * 8) = vv;
    }
    if (h == 0) __syncthreads();
  }
}

// ---------------- GEMM2 (MFMA, zero-LDS, hs-4 K-split -> 4 partial buffers, NO atomics) ----------------
__global__ __launch_bounds__(256) void k_gemm2(const bf16* __restrict__ attn_bf,
                                               const bf16* __restrict__ xb_bf,
                                               float* __restrict__ t2p) {
  int n = blockIdx.x;
  int b = n & 31;
  int r2 = n >> 5;                 // 0..63
  int kp = r2 & 3;
  int dgrp = (r2 >> 2) & 3;
  int hs = r2 >> 4;
  int tid = threadIdx.x;
  int wave = tid >> 6, lane = tid & 63;
  int wr = wave >> 1, wc = wave & 1;

  f32x4 acc[2][2];
#pragma unroll
  for (int i = 0; i < 2; i++)
#pragma unroll
    for (int j = 0; j < 2; j++) acc[i][j] = (f32x4){0.f, 0.f, 0.f, 0.f};

  const bf16* Abase = attn_bf + ((size_t)(b * 128 + hs * 32) * 1024 + (size_t)(kp * 4 + wr * 2) * 64) * 8;
  const bf16* Bbase = xb_bf + ((size_t)(b * 128 + hs * 32) * 1024 + (size_t)(dgrp * 4 + wc * 2) * 64) * 8;
#pragma unroll 4
  for (int st = 0; st < 32; st++) {
    const bf16* Ap = Abase + (size_t)st * 1024 * 8;
    const bf16* Bp = Bbase + (size_t)st * 1024 * 8;
    short8 a0 = *(const short8*)(Ap + (size_t)lane * 8);
    short8 a1 = *(const short8*)(Ap + (size_t)(64 + lane) * 8);
    short8 b0 = *(const short8*)(Bp + (size_t)lane * 8);
    short8 b1 = *(const short8*)(Bp + (size_t)(64 + lane) * 8);
    acc[0][0] = MFMA16(a0, b0, acc[0][0]);
    acc[0][1] = MFMA16(a0, b1, acc[0][1]);
    acc[1][0] = MFMA16(a1, b0, acc[1][0]);
    acc[1][1] = MFMA16(a1, b1, acc[1][1]);
  }
  float* dst = t2p + (size_t)hs * PKD;
  int quad = lane >> 4, nl = lane & 15;
#pragma unroll
  for (int i = 0; i < 2; i++)
#pragma unroll
    for (int r = 0; r < 4; r++) {
      int row = (b << 8) + kp * 64 + wr * 32 + i * 16 + quad * 4 + r;
#pragma unroll
      for (int j = 0; j < 2; j++) {
        int col = dgrp * 64 + wc * 32 + j * 16 + nl;
        dst[(size_t)row * Dd + col] = acc[i][j][r];
      }
    }
}

// ---------------- LN_pre: t = LN(sum(t2 partials)/S + tgt); also tbf (64-row-group frag order) ----------------
__global__ __launch_bounds__(64) void k_ln_pre(const float* __restrict__ t2p,
                                               const float* __restrict__ S,
                                               const float* __restrict__ tgt,
                                               const float* __restrict__ g,
                                               const float* __restrict__ be,
                                               float* __restrict__ t,
                                               bf16* __restrict__ tbf) {
  int row = blockIdx.x;
  int lane = threadIdx.x;
  float sInv = 1.0f / S[row];
  size_t off = (size_t)row * Dd + lane * 4;
  float4 a0 = *(const float4*)(t2p + off);
  float4 a1 = *(const float4*)(t2p + PKD + off);
  float4 a2 = *(const float4*)(t2p + 2 * PKD + off);
  float4 a3 = *(const float4*)(t2p + 3 * PKD + off);
  const float* pt = tgt + off;
  float v[4];
  v[0] = (a0.x + a1.x + a2.x + a3.x) * sInv + pt[0];
  v[1] = (a0.y + a1.y + a2.y + a3.y) * sInv + pt[1];
  v[2] = (a0.z + a1.z + a2.z + a3.z) * sInv + pt[2];
  v[3] = (a0.w + a1.w + a2.w + a3.w) * sInv + pt[3];
  float s1 = v[0] + v[1] + v[2] + v[3];
  float s2 = v[0] * v[0] + v[1] * v[1] + v[2] * v[2] + v[3] * v[3];
#pragma unroll
  for (int m = 32; m >= 1; m >>= 1) {
    s1 += __shfl_xor(s1, m, 64);
    s2 += __shfl_xor(s2, m, 64);
  }
  float mu = s1 * (1.0f / 256.0f);
  float var = s2 * (1.0f / 256.0f) - mu * mu;
  float rs = rsqrtf(fmaxf(var, 0.f) + LN_EPSf);
  float* po = t + (size_t)row * Dd + lane * 4;
  bf16 o[4] __attribute__((aligned(8)));
#pragma unroll
  for (int u = 0; u < 4; u++) {
    float val = (v[u] - mu) * rs * g[lane * 4 + u] + be[lane * 4 + u];
    po[u] = val;
    o[u] = f2b(val);
  }
  int s = lane >> 3;
  int q2 = (lane >> 1) & 3;
  int jh = (lane & 1) * 4;
  size_t fi = (size_t)(((row & 63) >> 4) * 64 + q2 * 16 + (row & 15));
  *(float2*)(tbf + ((size_t)((row >> 6) * 8 + s) * 256 + fi) * 8 + jh) = *(float2*)o;
}

// ---------------- k_ffn: FUSED FFN + LN_out. out = LN(relu(t@w1^T+b1)@w2^T + b2 + t) ----------------
// grid 256 (rg = 32-row group), 512 threads (8 waves). R13-proven.
__global__ __launch_bounds__(512, 2) void k_ffn(const bf16* __restrict__ tbf,
                                                const bf16* __restrict__ w1bf,
                                                const float* __restrict__ b1,
                                                const bf16* __restrict__ w2bf,
                                                const float* __restrict__ b2v,
                                                const float* __restrict__ t,
                                                const float* __restrict__ g3,
                                                const float* __restrict__ be3,
                                                float* __restrict__ out) {
  __shared__ __align__(16) char smem[33792];          // rp (8 KB) phase 1; vt (33792 B) phase 2
  bf16* rp = (bf16*)smem;                             // [2][2048]
  float* vt = (float*)smem;                           // [32][264] f32
  int rg = blockIdx.x;             // 0..255 (rows rg*32 .. +31)
  int tid = threadIdx.x;
  int wave = tid >> 6, lane = tid & 63;
  int quad = lane >> 4, nl = lane & 15;
  int mh = wave >> 2, fq = wave & 3;     // GEMM1 role
  int gg = rg >> 1, half = rg & 1;       // tbf 64-row group, half

  short8 af1[8];
  {
    const bf16* Ab = tbf + ((size_t)(gg * 8) * 256 + (size_t)((half * 2 + mh) * 64 + lane)) * 8;
#pragma unroll
    for (int s = 0; s < 8; s++) af1[s] = *(const short8*)(Ab + (size_t)s * 2048);
  }

  f32x4 acc2[2][2];
#pragma unroll
  for (int i = 0; i < 2; i++)
#pragma unroll
    for (int j = 0; j < 2; j++) acc2[i][j] = (f32x4){0.f, 0.f, 0.f, 0.f};

  int setw = fq >> 1;
  int q2w = (fq * 2 + (nl >> 3)) & 3;
  int jw = nl & 7;
  int dgrp2 = wave >> 1;
  int ntp0 = (wave & 1) * 2;

  auto G1 = [&](int cn) {
    f32x4 a1a = (f32x4){0.f, 0.f, 0.f, 0.f};
    f32x4 a1b = (f32x4){0.f, 0.f, 0.f, 0.f};
    const bf16* Bb1 = w1bf + ((size_t)(cn * 8) * 256 + (size_t)(fq * 64 + lane)) * 8;
#pragma unroll
    for (int s = 0; s < 8; s += 2) {
      short8 bv0 = *(const short8*)(Bb1 + (size_t)s * 2048);
      short8 bv1 = *(const short8*)(Bb1 + (size_t)(s + 1) * 2048);
      a1a = MFMA16(af1[s], bv0, a1a);
      a1b = MFMA16(af1[s + 1], bv1, a1b);
    }
    float bias = b1[cn * 64 + fq * 16 + nl];
    bf16* rpw = rp + (cn & 1) * 2048;
#pragma unroll
    for (int r = 0; r < 4; r++) {
      float hv = fmaxf(a1a[r] + a1b[r] + bias, 0.f);
      int fi = mh * 64 + q2w * 16 + quad * 4 + r;
      int fisw = fi ^ ((fi >> 3) & 3);
      rpw[(setw * 128 + fisw) * 8 + jw] = f2b(hv);
    }
  };

  G1(0);
  __syncthreads();

#pragma unroll 1
  for (int c = 0; c < 32; c++) {
    if (c < 31) G1(c + 1);
    const bf16* rpr = rp + (c & 1) * 2048;
#pragma unroll
    for (int ks = 0; ks < 2; ks++) {
      short8 a2[2];
#pragma unroll
      for (int mi = 0; mi < 2; mi++) {
        int fi = mi * 64 + lane;
        int fisw = fi ^ ((fi >> 3) & 3);
        a2[mi] = *(const short8*)(rpr + (ks * 128 + fisw) * 8);
      }
      int sg = c * 2 + ks;
#pragma unroll
      for (int nt = 0; nt < 2; nt++) {
        short8 b2 = *(const short8*)(w2bf + ((size_t)(dgrp2 * 64 + sg) * 256 + (size_t)((ntp0 + nt) * 64 + lane)) * 8);
        acc2[0][nt] = MFMA16(a2[0], b2, acc2[0][nt]);
        acc2[1][nt] = MFMA16(a2[1], b2, acc2[1][nt]);
      }
    }
    __syncthreads();   // also fences rp before vt overwrite in the epilogue
  }

  // ---- epilogue pass A: stage o2 tile into vt (rp is dead past the last barrier) ----
#pragma unroll
  for (int mi = 0; mi < 2; mi++)
#pragma unroll
    for (int r = 0; r < 4; r++) {
      int lrow = mi * 16 + quad * 4 + r;
#pragma unroll
      for (int nt = 0; nt < 2; nt++) {
        int col = wave * 32 + nt * 16 + nl;
        vt[lrow * 264 + col] = acc2[mi][nt][r];
      }
    }
  __syncthreads();

  // ---- epilogue pass B: per-row LN; wave w owns rows 4w..4w+3, lane = one float4 per row ----
  const float4 bv = *(const float4*)(b2v + lane * 4);
  const float4 gv = *(const float4*)(g3 + lane * 4);
  const float4 ev = *(const float4*)(be3 + lane * 4);
#pragma unroll
  for (int rr = 0; rr < 4; rr++) {
    int lrow = wave * 4 + rr;
    int grow = rg * 32 + lrow;
    float4 a = *(const float4*)(vt + lrow * 264 + lane * 4);
    float4 tv = *(const float4*)(t + (size_t)grow * Dd + lane * 4);
    float v0 = a.x + bv.x + tv.x;
    float v1 = a.y + bv.y + tv.y;
    float v2 = a.z + bv.z + tv.z;
    float v3 = a.w + bv.w + tv.w;
    float s1 = v0 + v1 + v2 + v3;
    float s2 = v0 * v0 + v1 * v1 + v2 * v2 + v3 * v3;
#pragma unroll
    for (int m = 32; m >= 1; m >>= 1) {
      s1 += __shfl_xor(s1, m, 64);
      s2 += __shfl_xor(s2, m, 64);
    }
    float mu = s1 * (1.0f / 256.0f);
    float var = s2 * (1.0f / 256.0f) - mu * mu;
    float rsv = rsqrtf(fmaxf(var, 0.f) + LN_EPSf);
    float4 o;
    o.x = (v0 - mu) * rsv * gv.x + ev.x;
    o.y = (v1 - mu) * rsv * gv.y + ev.y;
    o.z = (v2 - mu) * rsv * gv.z + ev.z;
    o.w = (v3 - mu) * rsv * gv.w + ev.w;
    *(float4*)(out + (size_t)grow * Dd + lane * 4) = o;
  }
}

extern "C" void kernel_launch(void* const* d_in, const int* in_sizes, int n_in,
                              void* d_out, int out_size, void* d_ws, size_t ws_size,
                              hipStream_t stream) {
  const float* x = (const float*)d_in[0];
  const float* tgt = (const float*)d_in[1];
  const float* w1 = (const float*)d_in[2];
  const float* b1 = (const float*)d_in[3];
  const float* w2 = (const float*)d_in[4];
  const float* b2v = (const float*)d_in[5];
  const float* g2 = (const float*)d_in[6];
  const float* be2 = (const float*)d_in[7];
  const float* g3 = (const float*)d_in[8];
  const float* be3 = (const float*)d_in[9];
  float* out = (float*)d_out;

  // Aliasing:
  //   tbf -> tnbf (dead after k_dots)
  //   w1bf/w2bf DEDICATED (+2MB; total 174MB <= 180MB baseline-proven) -> k_prew merged into k_tnw
  //   t2 partials (4x8MB = 32MB) -> h1reg region (read by ln_pre)
  //   o2 eliminated (LN fused into k_ffn)
  char* w = (char*)d_ws;
  bf16* tnbf = (bf16*)w;     w += (size_t)Bb * Kk * Dd * 2;   // 4 MB
  float* S = (float*)w;      w += (size_t)Bb * Kk * 4;        // 32 KB
  float* t = (float*)w;      w += (size_t)Bb * Kk * Dd * 4;   // 8 MB
  bf16* attn_bf = (bf16*)w;  w += (size_t)Bb * HWw * Kk * 2;  // 64 MB
  bf16* h1reg = (bf16*)w;    w += (size_t)Bb * Kk * Ff * 2;   // 32 MB (t2p lives here)
  bf16* xb_bf = (bf16*)w;    w += (size_t)Bb * Dd * HWw * 2;  // 64 MB
  bf16* w1bf = (bf16*)w;     w += (size_t)Ff * Dd * 2;        // 1 MB (dedicated)
  bf16* w2bf = (bf16*)w;     w += (size_t)Dd * Ff * 2;        // 1 MB (dedicated)

  bf16* tbf = tnbf;                        // 4 MB alias
  float* t2p = (float*)h1reg;              // 32 MB alias (4 partials)

  k_tnw<<<Bb * Kk + Ff + Dd, 64, 0, stream>>>(tgt, tnbf, S, w1, w2, w1bf, w2bf);
  k_dots<<<Bb * (HWw / 64), 256, 0, stream>>>(tnbf, x, xb_bf, attn_bf, S);
  k_gemm2<<<2048, 256, 0, stream>>>(attn_bf, xb_bf, t2p);
  k_ln_pre<<<Bb * Kk, 64, 0, stream>>>(t2p, S, tgt, g2, be2, t, tbf);
  k_ffn<<<(Bb * Kk) / 32, 512, 0, stream>>>(tbf, w1bf, b1, w2bf, b2v, t, g3, be3, out);
}

// Round 15
// 373.476 us; speedup vs baseline: 1.0663x; 1.0663x over previous
//
#include <hip/hip_runtime.h>
#include <hip/hip_bf16.h>

using bf16 = __hip_bfloat16;

typedef __attribute__((ext_vector_type(8))) short short8;
typedef __attribute__((ext_vector_type(4))) float f32x4;

constexpr int Bb = 32, Dd = 256, HWw = 4096, Kk = 256, Ff = 2048;
constexpr float TEMP_INV = 1.0f / 0.07f;
constexpr float EPSf = 1e-6f;
constexpr float NORM_EPSf = 1e-12f;
constexpr float LN_EPSf = 1e-5f;
constexpr size_t PKD = (size_t)Bb * Kk * Dd;   // one t2 partial (2M floats = 8 MB)

static __device__ __forceinline__ float b2f(bf16 v) { return __bfloat162float(v); }
static __device__ __forceinline__ bf16 f2b(float v) { return __float2bfloat16(v); }

// Fragment-order conventions (16x16x32 MFMA, K-step 32):
//   element (row, k): set = k>>5, q2 = (k>>3)&3, j = k&7
//   256-row group (tnbf, attn_bf, xb_bf): fi = (row>>4)*64 + q2*16 + (row&15); 1024 frags/step
//   64-row group (w1bf/w2bf):             fi = ((row&63)>>4)*64 + q2*16 + (row&15); 256 frags/step
//   A-frag identity: frag(mt, lane) set s = row = mt*16+(lane&15), k = s*32 + (lane>>4)*8 + j
//     -> af[s] = 8 consecutive k of one row (enables direct f32-row -> frag conversion)
// LDS repack swizzle (bank-spread, involution): fi_sw = fi ^ ((fi>>3)&3)
//
// Config provenance (measured):
//   k_dots: R5/R10 pair-wise hw-64 + bounds(256,3), VGPR 80 -> 90-108 us session-dependent.
//   k_gemm2: R8 hs-4 K-split partials, grid 2048.
//   k_ffn: ffn1+ffn2+LN_out (R13) + THIS ROUND LN_pre phase-0 (t/tbf never touch HBM;
//     ln_pre dispatch removed; 4 dispatches total). Evidence R7-R14: dispatch removal ~4-15 us.

// ---------------- k_tnw: tn (l2norm tgt -> tnbf, zero S) + prew (w1/w2 -> frag order) ----------------
__global__ __launch_bounds__(64) void k_tnw(const float* __restrict__ tgt,
                                            bf16* __restrict__ tnbf,
                                            float* __restrict__ S,
                                            const float* __restrict__ w1,
                                            const float* __restrict__ w2,
                                            bf16* __restrict__ w1bf,
                                            bf16* __restrict__ w2bf) {
  int bidx = blockIdx.x;
  int lane = threadIdx.x;
  if (bidx < Bb * Kk) {
    int row = bidx;                // b*256 + slot
    int b = row >> 8, slot = row & 255;
    if (lane == 0) S[row] = 0.f;   // replaces hipMemsetAsync(S) (k_dots runs after)
    const float* src = tgt + (size_t)row * Dd + lane * 4;
    float v[4];
#pragma unroll
    for (int u = 0; u < 4; u++) v[u] = src[u];
    float ss = v[0] * v[0] + v[1] * v[1] + v[2] * v[2] + v[3] * v[3];
#pragma unroll
    for (int m = 32; m >= 1; m >>= 1) ss += __shfl_xor(ss, m, 64);
    float inv = 1.0f / fmaxf(sqrtf(ss), NORM_EPSf);
    bf16 o[4] __attribute__((aligned(8)));
#pragma unroll
    for (int u = 0; u < 4; u++) o[u] = f2b(v[u] * inv);
    int s = lane >> 3;
    int q2 = (lane >> 1) & 3;
    int jh = (lane & 1) * 4;
    size_t fi = (size_t)((slot >> 4) * 64 + q2 * 16 + (slot & 15));
    *(float2*)(tnbf + ((size_t)(b * 8 + s) * 1024 + fi) * 8 + jh) = *(float2*)o;
  } else if (bidx < Bb * Kk + Ff) {
    int f = bidx - Bb * Kk;        // 0..2047
    const float* src = w1 + (size_t)f * Dd + lane * 4;
    bf16 o[4] __attribute__((aligned(8)));
#pragma unroll
    for (int u = 0; u < 4; u++) o[u] = f2b(src[u]);
    int s = lane >> 3;
    int q2 = (lane >> 1) & 3;
    int jh = (lane & 1) * 4;
    size_t fi = (size_t)(((f & 63) >> 4) * 64 + q2 * 16 + (f & 15));
    *(float2*)(w1bf + ((size_t)((f >> 6) * 8 + s) * 256 + fi) * 8 + jh) = *(float2*)o;
  } else {
    int d = bidx - Bb * Kk - Ff;   // 0..255
    const float* src = w2 + (size_t)d * Ff + lane * 32;
    size_t gbase = (size_t)((d >> 6) * 64 + lane) * 256;
    int fbase = ((d & 63) >> 4) * 64 + (d & 15);
#pragma unroll
    for (int q2 = 0; q2 < 4; q2++) {
      float4 v0 = *(const float4*)(src + q2 * 8);
      float4 v1 = *(const float4*)(src + q2 * 8 + 4);
      bf16 o[8] __attribute__((aligned(16)));
      o[0] = f2b(v0.x); o[1] = f2b(v0.y); o[2] = f2b(v0.z); o[3] = f2b(v0.w);
      o[4] = f2b(v1.x); o[5] = f2b(v1.y); o[6] = f2b(v1.z); o[7] = f2b(v1.w);
      *(float4*)(w2bf + (gbase + fbase + q2 * 16) * 8) = *(float4*)o;
    }
  }
}

#define MFMA16(a, b, c) __builtin_amdgcn_mfma_f32_16x16x32_bf16(a, b, c, 0, 0, 0)

// ---------------- k_dots: softmax(slots) -> attn_bf (frag order), xb_bf (frag order), S ----------------
// R5 config: pair-wise double-buffered pipeline at 3 waves/SIMD, bounds(256,3), VGPR 80.
__global__ __launch_bounds__(256, 3) void k_dots(const bf16* __restrict__ tnbf,
                                                 const float* __restrict__ x,
                                                 bf16* __restrict__ xb_bf,
                                                 bf16* __restrict__ attn_bf,
                                                 float* __restrict__ S) {
  __shared__ __align__(16) char smem[23296];
  bf16* Bs = (bf16*)smem;                    // [4][2080]
  float* ssred = (float*)(smem + 16640);     // [64*17]
  float* nxl = (float*)(smem + 20992);       // [64]
  float* red = (float*)(smem + 21248);       // [512]
  int b = blockIdx.x >> 6;
  int hw0 = (blockIdx.x & 63) * 64;
  int tid = threadIdx.x;
  int wave = tid >> 6, lane = tid & 63;
  int quad = lane >> 4, nl = lane & 15;

  int dp = tid >> 4;           // 0..15
  int ch = tid & 15;           // 0..15
  int qb = dp >> 2;
  int jb = (dp & 3) * 2;

  f32x4 acc[4][4];
#pragma unroll
  for (int i = 0; i < 4; i++)
#pragma unroll
    for (int j = 0; j < 4; j++) acc[i][j] = (f32x4){0.f, 0.f, 0.f, 0.f};
  float ssp[4] = {0.f, 0.f, 0.f, 0.f};

  int spx = (hw0 >> 5) + (ch >> 3);
  int q2x = (ch >> 1) & 3;
  int jx = (ch & 1) * 4;

  const float* xbase = x + (size_t)((b << 8) + 2 * dp) * HWw + hw0 + ch * 4;
  float4 va4[2], vb4[2];
#pragma unroll
  for (int q = 0; q < 2; q++) {
    const float* xr = xbase + (size_t)(q * 32) * HWw;
    va4[q] = *(const float4*)xr;
    vb4[q] = *(const float4*)(xr + HWw);
  }
  short8 afp[4];
  {
    const bf16* ts0 = tnbf + (size_t)(b * 8) * 1024 * 8;
#pragma unroll
    for (int mt = 0; mt < 4; mt++)
      afp[mt] = *(const short8*)(ts0 + (size_t)(((wave << 2) + mt) * 64 + lane) * 8);
  }

#pragma unroll 1
  for (int p = 0; p < 4; p++) {
    bf16* bsb = Bs + (p & 1) * 2 * 2080;
    bf16 paS[2][4] __attribute__((aligned(8)));
    bf16 pbS[2][4] __attribute__((aligned(8)));
#pragma unroll
    for (int q = 0; q < 2; q++) {
      float vva[4] = {va4[q].x, va4[q].y, va4[q].z, va4[q].w};
      float vvb[4] = {vb4[q].x, vb4[q].y, vb4[q].z, vb4[q].w};
#pragma unroll
      for (int jj = 0; jj < 4; jj++) {
        ssp[jj] += vva[jj] * vva[jj] + vvb[jj] * vvb[jj];
        paS[q][jj] = f2b(vva[jj]);
        pbS[q][jj] = f2b(vvb[jj]);
      }
#pragma unroll
      for (int jj = 0; jj < 4; jj++) {
        int hwl = ch * 4 + jj;
        int nt = hwl >> 4;
        int li = (qb << 4) | (hwl & 15);
        union { bf16 h[2]; unsigned int u; } pk;
        pk.h[0] = paS[q][jj];
        pk.h[1] = pbS[q][jj];
        *(unsigned int*)&bsb[q * 2080 + nt * 520 + li * 8 + jb] = pk.u;
      }
    }
    __syncthreads();

#pragma unroll
    for (int q = 0; q < 2; q++) {
      int s = 2 * p + q;
      int d0r = s * 32 + 2 * dp;
      int fiA = (d0r >> 4) * 64 + q2x * 16 + (d0r & 15);
      size_t base = ((size_t)(b * 128) + spx) * 1024;
      *(float2*)(xb_bf + (base + fiA) * 8 + jx) = *(float2*)paS[q];
      *(float2*)(xb_bf + (base + fiA + 1) * 8 + jx) = *(float2*)pbS[q];
    }
    if (p < 3) {
#pragma unroll
      for (int q = 0; q < 2; q++) {
        const float* xr = xbase + (size_t)(((p + 1) * 2 + q) * 32) * HWw;
        va4[q] = *(const float4*)xr;
        vb4[q] = *(const float4*)(xr + HWw);
      }
    }
#pragma unroll
    for (int q = 0; q < 2; q++) {
      int s = 2 * p + q;
      short8 af[4];
#pragma unroll
      for (int mt = 0; mt < 4; mt++) af[mt] = afp[mt];
      if (s < 7) {
        const bf16* tsrc = tnbf + (size_t)(b * 8 + s + 1) * 1024 * 8;
#pragma unroll
        for (int mt = 0; mt < 4; mt++)
          afp[mt] = *(const short8*)(tsrc + (size_t)(((wave << 2) + mt) * 64 + lane) * 8);
      }
      short8 bfv[4];
#pragma unroll
      for (int nt = 0; nt < 4; nt++)
        bfv[nt] = *(const short8*)(bsb + q * 2080 + nt * 520 + lane * 8);
#pragma unroll
      for (int mt = 0; mt < 4; mt++)
#pragma unroll
        for (int nt = 0; nt < 4; nt++) acc[mt][nt] = MFMA16(af[mt], bfv[nt], acc[mt][nt]);
    }
  }

#pragma unroll
  for (int jj = 0; jj < 4; jj++) ssred[(ch * 4 + jj) * 17 + dp] = ssp[jj];
  __syncthreads();
  if (tid < 64) {
    float sum = 0.f;
#pragma unroll
    for (int i = 0; i < 16; i++) sum += ssred[tid * 17 + i];
    nxl[tid] = TEMP_INV / fmaxf(sqrtf(sum), NORM_EPSf);
  }
  __syncthreads();

  float sc[4];
#pragma unroll
  for (int nt = 0; nt < 4; nt++) sc[nt] = nxl[nt * 16 + nl];
#pragma unroll
  for (int mt = 0; mt < 4; mt++)
#pragma unroll
    for (int nt = 0; nt < 4; nt++)
#pragma unroll
      for (int r = 0; r < 4; r++) acc[mt][nt][r] *= sc[nt];

  float* red2 = red + 256;

  float pmax[4];
#pragma unroll
  for (int nt = 0; nt < 4; nt++) {
    float m = acc[0][nt][0];
#pragma unroll
    for (int mt = 0; mt < 4; mt++)
#pragma unroll
      for (int r = 0; r < 4; r++) m = fmaxf(m, acc[mt][nt][r]);
    m = fmaxf(m, __shfl_xor(m, 16, 64));
    m = fmaxf(m, __shfl_xor(m, 32, 64));
    pmax[nt] = m;
  }
  if (lane < 16) {
#pragma unroll
    for (int nt = 0; nt < 4; nt++) red[((wave << 2) + nt) * 16 + nl] = pmax[nt];
  }
  __syncthreads();
  float cmax[4];
#pragma unroll
  for (int nt = 0; nt < 4; nt++) {
    float m = red[nt * 16 + nl];
#pragma unroll
    for (int w2 = 1; w2 < 4; w2++) m = fmaxf(m, red[((w2 << 2) + nt) * 16 + nl]);
    cmax[nt] = m;
  }

  float psum[4];
#pragma unroll
  for (int nt = 0; nt < 4; nt++) {
    float s = 0.f;
#pragma unroll
    for (int mt = 0; mt < 4; mt++)
#pragma unroll
      for (int r = 0; r < 4; r++) {
        float e = __expf(acc[mt][nt][r] - cmax[nt]);
        acc[mt][nt][r] = e;
        s += e;
      }
    s += __shfl_xor(s, 16, 64);
    s += __shfl_xor(s, 32, 64);
    psum[nt] = s;
  }
  if (lane < 16) {
#pragma unroll
    for (int nt = 0; nt < 4; nt++) red2[((wave << 2) + nt) * 16 + nl] = psum[nt];
  }
  __syncthreads();
  float ci[4];
#pragma unroll
  for (int nt = 0; nt < 4; nt++) {
    float s = 0.f;
#pragma unroll
    for (int w2 = 0; w2 < 4; w2++) s += red2[((w2 << 2) + nt) * 16 + nl];
    ci[nt] = 1.0f / s;
  }

#pragma unroll
  for (int mt = 0; mt < 4; mt++) {
    int slotg = (b << 8) + (wave << 6) + (mt << 4) + (quad << 2);
#pragma unroll
    for (int r = 0; r < 4; r++) {
      float rs = 0.f;
#pragma unroll
      for (int nt = 0; nt < 4; nt++) {
        bf16 hb = f2b(acc[mt][nt][r] * ci[nt] + EPSf);
        float q = b2f(hb);
        acc[mt][nt][r] = q;
        rs += q;
      }
      rs += __shfl_xor(rs, 1, 64);
      rs += __shfl_xor(rs, 2, 64);
      rs += __shfl_xor(rs, 4, 64);
      rs += __shfl_xor(rs, 8, 64);
      if (nl == 0) atomicAdd(&S[slotg + r], rs);
    }
  }

  __syncthreads();
  bf16* rp = (bf16*)smem;
  int jat = nl & 7;
#pragma unroll
  for (int h = 0; h < 2; h++) {
#pragma unroll
    for (int mt = 0; mt < 4; mt++) {
      int fi0 = ((wave << 2) + mt) * 64 + (quad << 2);
#pragma unroll
      for (int ntl = 0; ntl < 2; ntl++) {
        int nt = (h << 1) + ntl;
        int q2p = (ntl << 1) + (nl >> 3);
#pragma unroll
        for (int r = 0; r < 4; r++) {
          int fi = fi0 + q2p * 16 + r;
          int fisw = fi ^ ((fi >> 3) & 3);
          rp[fisw * 8 + jat] = f2b(acc[mt][nt][r]);
        }
      }
    }
    __syncthreads();
    size_t gbase = ((size_t)(b * 128) + (hw0 >> 5) + h) * 1024 * 8;
#pragma unroll
    for (int u = 0; u < 4; u++) {
      int fl = u * 256 + tid;
      int fg = fl ^ ((fl >> 3) & 3);
      short8 vv = *(const short8*)(rp + (size_t)fl * 8);
      *(short8*)(attn_bf + gbase + (size_t)fg * 8) = vv;
    }
    if (h == 0) __syncthreads();
  }
}

// ---------------- GEMM2 (MFMA, zero-LDS, hs-4 K-split -> 4 partial buffers, NO atomics) ----------------
__global__ __launch_bounds__(256) void k_gemm2(const bf16* __restrict__ attn_bf,
                                               const bf16* __restrict__ xb_bf,
                                               float* __restrict__ t2p) {
  int n = blockIdx.x;
  int b = n & 31;
  int r2 = n >> 5;                 // 0..63
  int kp = r2 & 3;
  int dgrp = (r2 >> 2) & 3;
  int hs = r2 >> 4;
  int tid = threadIdx.x;
  int wave = tid >> 6, lane = tid & 63;
  int wr = wave >> 1, wc = wave & 1;

  f32x4 acc[2][2];
#pragma unroll
  for (int i = 0; i < 2; i++)
#pragma unroll
    for (int j = 0; j < 2; j++) acc[i][j] = (f32x4){0.f, 0.f, 0.f, 0.f};

  const bf16* Abase = attn_bf + ((size_t)(b * 128 + hs * 32) * 1024 + (size_t)(kp * 4 + wr * 2) * 64) * 8;
  const bf16* Bbase = xb_bf + ((size_t)(b * 128 + hs * 32) * 1024 + (size_t)(dgrp * 4 + wc * 2) * 64) * 8;
#pragma unroll 4
  for (int st = 0; st < 32; st++) {
    const bf16* Ap = Abase + (size_t)st * 1024 * 8;
    const bf16* Bp = Bbase + (size_t)st * 1024 * 8;
    short8 a0 = *(const short8*)(Ap + (size_t)lane * 8);
    short8 a1 = *(const short8*)(Ap + (size_t)(64 + lane) * 8);
    short8 b0 = *(const short8*)(Bp + (size_t)lane * 8);
    short8 b1 = *(const short8*)(Bp + (size_t)(64 + lane) * 8);
    acc[0][0] = MFMA16(a0, b0, acc[0][0]);
    acc[0][1] = MFMA16(a0, b1, acc[0][1]);
    acc[1][0] = MFMA16(a1, b0, acc[1][0]);
    acc[1][1] = MFMA16(a1, b1, acc[1][1]);
  }
  float* dst = t2p + (size_t)hs * PKD;
  int quad = lane >> 4, nl = lane & 15;
#pragma unroll
  for (int i = 0; i < 2; i++)
#pragma unroll
    for (int r = 0; r < 4; r++) {
      int row = (b << 8) + kp * 64 + wr * 32 + i * 16 + quad * 4 + r;
#pragma unroll
      for (int j = 0; j < 2; j++) {
        int col = dgrp * 64 + wc * 32 + j * 16 + nl;
        dst[(size_t)row * Dd + col] = acc[i][j][r];
      }
    }
}

// ---------------- k_ffn: LN_pre + FFN + LN_out, all in one kernel ----------------
// grid 256 (rg = 32-row group), 512 threads (8 waves).
// Phase 0: LN_pre for the block's 32 rows (sum 4 t2p partials, /S, +tgt, LN(g2,be2))
//          -> t_tile [32][264] f32 in LDS (stays live for final residual).
// af1 built directly from t_tile rows via A-frag identity (f2b = same rounding as old tbf).
// Main loop + LN_out epilogue: identical to R13-proven k_ffn (rp/vt in scratch region).
// LDS: t_tile @0 (33792 B) | scratch @33792 (33792 B: rp 8KB phase 1, vt phase 2) = 67584 B.
__global__ __launch_bounds__(512, 2) void k_ffn(const float* __restrict__ t2p,
                                                const float* __restrict__ S,
                                                const float* __restrict__ tgt,
                                                const float* __restrict__ g2,
                                                const float* __restrict__ be2,
                                                const bf16* __restrict__ w1bf,
                                                const float* __restrict__ b1,
                                                const bf16* __restrict__ w2bf,
                                                const float* __restrict__ b2v,
                                                const float* __restrict__ g3,
                                                const float* __restrict__ be3,
                                                float* __restrict__ out) {
  __shared__ __align__(16) char smem[67584];
  float* t_tile = (float*)smem;                       // [32][264] f32
  bf16* rp = (bf16*)(smem + 33792);                   // [2][2048] bf16 (phase 1)
  float* vt = (float*)(smem + 33792);                 // [32][264] f32 (phase 2)
  int rg = blockIdx.x;             // 0..255 (rows rg*32 .. +31)
  int tid = threadIdx.x;
  int wave = tid >> 6, lane = tid & 63;
  int quad = lane >> 4, nl = lane & 15;
  int mh = wave >> 2, fq = wave & 3;     // GEMM1 role

  // ---- phase 0: LN_pre for rows 4*wave .. +3 (lane = one float4 per row) ----
  {
    const float4 gv2 = *(const float4*)(g2 + lane * 4);
    const float4 ev2 = *(const float4*)(be2 + lane * 4);
#pragma unroll
    for (int rr = 0; rr < 4; rr++) {
      int lrow = wave * 4 + rr;
      int grow = rg * 32 + lrow;
      size_t off = (size_t)grow * Dd + lane * 4;
      float4 a0 = *(const float4*)(t2p + off);
      float4 a1 = *(const float4*)(t2p + PKD + off);
      float4 a2 = *(const float4*)(t2p + 2 * PKD + off);
      float4 a3 = *(const float4*)(t2p + 3 * PKD + off);
      float4 tgv = *(const float4*)(tgt + off);
      float sInv = 1.0f / S[grow];
      float v0 = (a0.x + a1.x + a2.x + a3.x) * sInv + tgv.x;
      float v1 = (a0.y + a1.y + a2.y + a3.y) * sInv + tgv.y;
      float v2 = (a0.z + a1.z + a2.z + a3.z) * sInv + tgv.z;
      float v3 = (a0.w + a1.w + a2.w + a3.w) * sInv + tgv.w;
      float s1 = v0 + v1 + v2 + v3;
      float s2 = v0 * v0 + v1 * v1 + v2 * v2 + v3 * v3;
#pragma unroll
      for (int m = 32; m >= 1; m >>= 1) {
        s1 += __shfl_xor(s1, m, 64);
        s2 += __shfl_xor(s2, m, 64);
      }
      float mu = s1 * (1.0f / 256.0f);
      float var = s2 * (1.0f / 256.0f) - mu * mu;
      float rsv = rsqrtf(fmaxf(var, 0.f) + LN_EPSf);
      float4 o;
      o.x = (v0 - mu) * rsv * gv2.x + ev2.x;
      o.y = (v1 - mu) * rsv * gv2.y + ev2.y;
      o.z = (v2 - mu) * rsv * gv2.z + ev2.z;
      o.w = (v3 - mu) * rsv * gv2.w + ev2.w;
      *(float4*)(t_tile + lrow * 264 + lane * 4) = o;
    }
  }
  __syncthreads();

  // ---- build af1 from t_tile via A-frag identity: row = mh*16+(lane&15), k = s*32+(lane>>4)*8+j ----
  short8 af1[8];
  {
    int arow = mh * 16 + nl;
    const float* trow = t_tile + arow * 264 + quad * 8;
#pragma unroll
    for (int s = 0; s < 8; s++) {
      float4 f0 = *(const float4*)(trow + s * 32);
      float4 f1 = *(const float4*)(trow + s * 32 + 4);
      bf16 ob[8] __attribute__((aligned(16)));
      ob[0] = f2b(f0.x); ob[1] = f2b(f0.y); ob[2] = f2b(f0.z); ob[3] = f2b(f0.w);
      ob[4] = f2b(f1.x); ob[5] = f2b(f1.y); ob[6] = f2b(f1.z); ob[7] = f2b(f1.w);
      af1[s] = *(const short8*)ob;
    }
  }

  f32x4 acc2[2][2];
#pragma unroll
  for (int i = 0; i < 2; i++)
#pragma unroll
    for (int j = 0; j < 2; j++) acc2[i][j] = (f32x4){0.f, 0.f, 0.f, 0.f};

  int setw = fq >> 1;
  int q2w = (fq * 2 + (nl >> 3)) & 3;
  int jw = nl & 7;
  int dgrp2 = wave >> 1;
  int ntp0 = (wave & 1) * 2;

  auto G1 = [&](int cn) {
    f32x4 a1a = (f32x4){0.f, 0.f, 0.f, 0.f};
    f32x4 a1b = (f32x4){0.f, 0.f, 0.f, 0.f};
    const bf16* Bb1 = w1bf + ((size_t)(cn * 8) * 256 + (size_t)(fq * 64 + lane)) * 8;
#pragma unroll
    for (int s = 0; s < 8; s += 2) {
      short8 bv0 = *(const short8*)(Bb1 + (size_t)s * 2048);
      short8 bv1 = *(const short8*)(Bb1 + (size_t)(s + 1) * 2048);
      a1a = MFMA16(af1[s], bv0, a1a);
      a1b = MFMA16(af1[s + 1], bv1, a1b);
    }
    float bias = b1[cn * 64 + fq * 16 + nl];
    bf16* rpw = rp + (cn & 1) * 2048;
#pragma unroll
    for (int r = 0; r < 4; r++) {
      float hv = fmaxf(a1a[r] + a1b[r] + bias, 0.f);
      int fi = mh * 64 + q2w * 16 + quad * 4 + r;
      int fisw = fi ^ ((fi >> 3) & 3);
      rpw[(setw * 128 + fisw) * 8 + jw] = f2b(hv);
    }
  };

  G1(0);
  __syncthreads();

#pragma unroll 1
  for (int c = 0; c < 32; c++) {
    if (c < 31) G1(c + 1);
    const bf16* rpr = rp + (c & 1) * 2048;
#pragma unroll
    for (int ks = 0; ks < 2; ks++) {
      short8 a2[2];
#pragma unroll
      for (int mi = 0; mi < 2; mi++) {
        int fi = mi * 64 + lane;
        int fisw = fi ^ ((fi >> 3) & 3);
        a2[mi] = *(const short8*)(rpr + (ks * 128 + fisw) * 8);
      }
      int sg = c * 2 + ks;
#pragma unroll
      for (int nt = 0; nt < 2; nt++) {
        short8 b2 = *(const short8*)(w2bf + ((size_t)(dgrp2 * 64 + sg) * 256 + (size_t)((ntp0 + nt) * 64 + lane)) * 8);
        acc2[0][nt] = MFMA16(a2[0], b2, acc2[0][nt]);
        acc2[1][nt] = MFMA16(a2[1], b2, acc2[1][nt]);
      }
    }
    __syncthreads();   // also fences rp before vt overwrite in the epilogue
  }

  // ---- epilogue pass A: stage o2 tile into vt (rp dead past the last barrier) ----
#pragma unroll
  for (int mi = 0; mi < 2; mi++)
#pragma unroll
    for (int r = 0; r < 4; r++) {
      int lrow = mi * 16 + quad * 4 + r;
#pragma unroll
      for (int nt = 0; nt < 2; nt++) {
        int col = wave * 32 + nt * 16 + nl;
        vt[lrow * 264 + col] = acc2[mi][nt][r];
      }
    }
  __syncthreads();

  // ---- epilogue pass B: LN_out; wave w owns rows 4w..4w+3, residual from t_tile ----
  const float4 bv = *(const float4*)(b2v + lane * 4);
  const float4 gv = *(const float4*)(g3 + lane * 4);
  const float4 ev = *(const float4*)(be3 + lane * 4);
#pragma unroll
  for (int rr = 0; rr < 4; rr++) {
    int lrow = wave * 4 + rr;
    int grow = rg * 32 + lrow;
    float4 a = *(const float4*)(vt + lrow * 264 + lane * 4);
    float4 tv = *(const float4*)(t_tile + lrow * 264 + lane * 4);
    float v0 = a.x + bv.x + tv.x;
    float v1 = a.y + bv.y + tv.y;
    float v2 = a.z + bv.z + tv.z;
    float v3 = a.w + bv.w + tv.w;
    float s1 = v0 + v1 + v2 + v3;
    float s2 = v0 * v0 + v1 * v1 + v2 * v2 + v3 * v3;
#pragma unroll
    for (int m = 32; m >= 1; m >>= 1) {
      s1 += __shfl_xor(s1, m, 64);
      s2 += __shfl_xor(s2, m, 64);
    }
    float mu = s1 * (1.0f / 256.0f);
    float var = s2 * (1.0f / 256.0f) - mu * mu;
    float rsv = rsqrtf(fmaxf(var, 0.f) + LN_EPSf);
    float4 o;
    o.x = (v0 - mu) * rsv * gv.x + ev.x;
    o.y = (v1 - mu) * rsv * gv.y + ev.y;
    o.z = (v2 - mu) * rsv * gv.z + ev.z;
    o.w = (v3 - mu) * rsv * gv.w + ev.w;
    *(float4*)(out + (size_t)grow * Dd + lane * 4) = o;
  }
}

extern "C" void kernel_launch(void* const* d_in, const int* in_sizes, int n_in,
                              void* d_out, int out_size, void* d_ws, size_t ws_size,
                              hipStream_t stream) {
  const float* x = (const float*)d_in[0];
  const float* tgt = (const float*)d_in[1];
  const float* w1 = (const float*)d_in[2];
  const float* b1 = (const float*)d_in[3];
  const float* w2 = (const float*)d_in[4];
  const float* b2v = (const float*)d_in[5];
  const float* g2 = (const float*)d_in[6];
  const float* be2 = (const float*)d_in[7];
  const float* g3 = (const float*)d_in[8];
  const float* be3 = (const float*)d_in[9];
  float* out = (float*)d_out;

  // Aliasing:
  //   w1bf/w2bf dedicated (+2MB; total 166MB <= 180MB baseline-proven)
  //   t2 partials (4x8MB = 32MB) -> h1reg region (read by k_ffn phase 0)
  //   t/tbf/o2 eliminated (LN_pre + LN_out fused into k_ffn; t lives in LDS)
  char* w = (char*)d_ws;
  bf16* tnbf = (bf16*)w;     w += (size_t)Bb * Kk * Dd * 2;   // 4 MB
  float* S = (float*)w;      w += (size_t)Bb * Kk * 4;        // 32 KB
  bf16* attn_bf = (bf16*)w;  w += (size_t)Bb * HWw * Kk * 2;  // 64 MB
  bf16* h1reg = (bf16*)w;    w += (size_t)Bb * Kk * Ff * 2;   // 32 MB (t2p lives here)
  bf16* xb_bf = (bf16*)w;    w += (size_t)Bb * Dd * HWw * 2;  // 64 MB
  bf16* w1bf = (bf16*)w;     w += (size_t)Ff * Dd * 2;        // 1 MB (dedicated)
  bf16* w2bf = (bf16*)w;     w += (size_t)Dd * Ff * 2;        // 1 MB (dedicated)

  float* t2p = (float*)h1reg;              // 32 MB alias (4 partials)

  k_tnw<<<Bb * Kk + Ff + Dd, 64, 0, stream>>>(tgt, tnbf, S, w1, w2, w1bf, w2bf);
  k_dots<<<Bb * (HWw / 64), 256, 0, stream>>>(tnbf, x, xb_bf, attn_bf, S);
  k_gemm2<<<2048, 256, 0, stream>>>(attn_bf, xb_bf, t2p);
  k_ffn<<<(Bb * Kk) / 32, 512, 0, stream>>>(t2p, S, tgt, g2, be2, w1bf, b1, w2bf, b2v, g3, be3, out);
}